// Round 4
// baseline (705.546 us; speedup 1.0000x reference)
//
#include <hip/hip_runtime.h>

// ComplexAttention: B=4, S=2048, D=1024. Reduces to single-head attention with
// head_dim 2*D=2048:  Q/K/V = X@W^T+b ; S = Q@K^T/32 ; P = softmax(S) ; O = P@V ;
// out = O@Wo^T + bo.  GEMMs: 256x256 8-phase bf16 MFMA, ds_reads pipelined 1 phase ahead.
// R4: __launch_bounds__(512,2) -> 256-VGPR cap (LDS already limits to 1 block/CU, so free).

typedef short  bf16x8 __attribute__((ext_vector_type(8)));
typedef float  f32x4  __attribute__((ext_vector_type(4)));
typedef unsigned short u16;

typedef __attribute__((address_space(3))) void       lds_void;
typedef const __attribute__((address_space(1))) void g_void;

__device__ __forceinline__ u16 f2bf(float f) {
  union { float f; unsigned u; } v; v.f = f;
  unsigned r = v.u + 0x7FFFu + ((v.u >> 16) & 1u);   // round-to-nearest-even
  return (u16)(r >> 16);
}

// ---------------- fp32 -> bf16 convert (vectorized) ----------------
__global__ __launch_bounds__(256) void cvt_f32_bf16(const float* __restrict__ in,
                                                    u16* __restrict__ out, int n4) {
  int i = blockIdx.x * 256 + threadIdx.x;
  if (i >= n4) return;
  const float4 v = ((const float4*)in)[i];
  union { u16 us[4]; unsigned long long ll; } u;
  u.us[0] = f2bf(v.x); u.us[1] = f2bf(v.y); u.us[2] = f2bf(v.z); u.us[3] = f2bf(v.w);
  ((unsigned long long*)out)[i] = u.ll;
}

// ---------------- 256x256 8-phase NT GEMM, 1-phase-ahead ds_read pipeline ------
// C[m,n] = alpha * sum_k A[m,k]*B[n,k] (+ bias[n]).  A,B bf16 row-major (K contig).
// CMODE: 0 = fp32 C, 1 = bf16 C, 2 = bf16 transposed-V write Vt[b][n][t].
// 512 thr = 8 waves (2M x 4N); per-wave 128x64; BK=64; LDS 128 KiB dbuf; XOR swizzle.
// Per phase: [pre-read frags for NEXT phase] [stage 1 half-tile] [counted vmcnt]
//            [barrier] [16 MFMA setprio-wrapped] [barrier].
// vmcnt: p1:8, p2:4, p5:8, p6:4 (last iter 8,2,0,-) -- derived from queue simulation;
// every vmcnt precedes a barrier that precedes the dependent ds_reads (cross-wave safe).
template<int CMODE, bool BIAS>
__global__ __launch_bounds__(512, 2) void gemm256(const u16* __restrict__ A,
                                                  const u16* __restrict__ B,
                                                  void* __restrict__ Cv,
                                                  const float* __restrict__ bias,
                                                  int K, int lda, int ldb, int ldc,
                                                  long bsA, long bsB, long bsC,
                                                  float alpha)
{
  __shared__ u16 sm[65536];                  // A: [2][256][64] @ 0 ; B: same @ 32768
  const int bz = blockIdx.z;
  const u16* Ab = A + (long)bz * bsA;
  const u16* Bb = B + (long)bz * bsB;
  const int m0 = blockIdx.y * 256, n0 = blockIdx.x * 256;
  const int tid = threadIdx.x, lane = tid & 63, w = tid >> 6;
  const int wmr = w >> 2, wnr = w & 3;
  const int fr = lane & 15, ko = lane >> 4;

  f32x4 acc[8][4] = {};
  bf16x8 afA[8], afB[8], bfA[4], bfB[4];

  auto STAGE = [&](int dbuf, int half, int t, bool isA) {
    const u16* src = isA ? Ab : Bb;
    const int ld = isA ? lda : ldb;
    const int r0 = (isA ? m0 : n0) + half * 128;
    u16* lb = sm + (isA ? 0 : 32768) + dbuf * 16384 + half * 8192;
#pragma unroll
    for (int q = 0; q < 2; ++q) {
      const int slot = q * 512 + w * 64 + lane;
      const int rl = slot >> 3, cc = slot & 7;
      const int c = cc ^ (rl & 7);
      __builtin_amdgcn_global_load_lds(
          (g_void*)(src + (long)(r0 + rl) * ld + t * 64 + c * 8),
          (lds_void*)(lb + q * 4096 + w * 512), 16, 0, 0);
    }
  };
  auto LDA_f = [&](bf16x8* dst, int dbuf, int mh) {
#pragma unroll
    for (int mi = 0; mi < 4; ++mi)
#pragma unroll
      for (int kk = 0; kk < 2; ++kk) {
        const int r = wmr * 128 + mh * 64 + mi * 16 + fr;
        const int c = kk * 4 + ko;
        dst[mi * 2 + kk] = *(const bf16x8*)(sm + dbuf * 16384 + r * 64 + ((c ^ (r & 7)) * 8));
      }
  };
  auto LDB_f = [&](bf16x8* dst, int dbuf, int nh) {
#pragma unroll
    for (int ni = 0; ni < 2; ++ni)
#pragma unroll
      for (int kk = 0; kk < 2; ++kk) {
        const int r = wnr * 64 + nh * 32 + ni * 16 + fr;
        const int c = kk * 4 + ko;
        dst[ni * 2 + kk] = *(const bf16x8*)(sm + 32768 + dbuf * 16384 + r * 64 + ((c ^ (r & 7)) * 8));
      }
  };
  auto MM = [&](const bf16x8* af, const bf16x8* bf, int mb, int nb) {
    __builtin_amdgcn_s_setprio(1);
#pragma unroll
    for (int mi = 0; mi < 4; ++mi)
#pragma unroll
      for (int ni = 0; ni < 2; ++ni)
#pragma unroll
        for (int kk = 0; kk < 2; ++kk)
          acc[mb + mi][nb + ni] = __builtin_amdgcn_mfma_f32_16x16x32_bf16(
              af[mi * 2 + kk], bf[ni * 2 + kk], acc[mb + mi][nb + ni], 0, 0, 0);
    __builtin_amdgcn_s_setprio(0);
  };

  const int nt = K >> 6, niter = nt >> 1;

  // prologue: b0 full (t0=0), then b1 B0,B1,A0 (t1=1); drain b0; pre-read Q00 frags.
  STAGE(0, 0, 0, true);  STAGE(0, 1, 0, true);
  STAGE(0, 0, 0, false); STAGE(0, 1, 0, false);
  STAGE(1, 0, 1, false); STAGE(1, 1, 1, false);
  STAGE(1, 0, 1, true);
  asm volatile("s_waitcnt vmcnt(6)" ::: "memory");
  __builtin_amdgcn_s_barrier();
  LDA_f(afA, 0, 0); LDB_f(bfA, 0, 0);

  auto ITER = [&](int j, bool pre) {
    const int t1 = 2 * j + 1, tn = 2 * j + 2;
    // p1: MM Q00(t0)=afA*bfA | pre bfB=bf1(b0) | S1=A1(t1)->b1 | vmcnt(8)
    LDB_f(bfB, 0, 1);
    STAGE(1, 1, t1, true);
    asm volatile("s_waitcnt vmcnt(8)" ::: "memory");
    __builtin_amdgcn_s_barrier();
    MM(afA, bfA, 0, 0);
    __builtin_amdgcn_s_barrier();
    // p2: MM Q01(t0)=afA*bfB | pre afB=af1(b0) | S2=B0(tn)->b0 | vmcnt(4|2)
    LDA_f(afB, 0, 1);
    if (pre) { STAGE(0, 0, tn, false); asm volatile("s_waitcnt vmcnt(4)" ::: "memory"); }
    else     { asm volatile("s_waitcnt vmcnt(2)" ::: "memory"); }
    __builtin_amdgcn_s_barrier();
    MM(afA, bfB, 0, 2);
    __builtin_amdgcn_s_barrier();
    // p3: MM Q11(t0)=afB*bfB | pre afA=af0(b1,t1) | S3=B1(tn)->b0
    LDA_f(afA, 1, 0);
    if (pre) STAGE(0, 1, tn, false);
    __builtin_amdgcn_s_barrier();
    MM(afB, bfB, 4, 2);
    __builtin_amdgcn_s_barrier();
    // p4: MM Q10(t0)=afB*bfA | pre bfB=bf1(b1,t1) | S4=A0(tn)->b0
    LDB_f(bfB, 1, 1);
    if (pre) STAGE(0, 0, tn, true);
    __builtin_amdgcn_s_barrier();
    MM(afB, bfA, 4, 0);
    __builtin_amdgcn_s_barrier();
    // p5: MM Q01(t1)=afA*bfB | pre bfA=bf0(b1,t1) | S5=A1(tn)->b0 | vmcnt(8|0)
    LDB_f(bfA, 1, 0);
    if (pre) { STAGE(0, 1, tn, true); asm volatile("s_waitcnt vmcnt(8)" ::: "memory"); }
    else     { asm volatile("s_waitcnt vmcnt(0)" ::: "memory"); }
    __builtin_amdgcn_s_barrier();
    MM(afA, bfB, 0, 2);
    __builtin_amdgcn_s_barrier();
    // p6: MM Q00(t1)=afA*bfA | pre afB=af1(b1,t1) | S6=B0(t1+2)->b1 | vmcnt(4)
    LDA_f(afB, 1, 1);
    if (pre) { STAGE(1, 0, t1 + 2, false); asm volatile("s_waitcnt vmcnt(4)" ::: "memory"); }
    __builtin_amdgcn_s_barrier();
    MM(afA, bfA, 0, 0);
    __builtin_amdgcn_s_barrier();
    // p7: MM Q10(t1)=afB*bfA | pre afA=af0(b0,tn) | S7=B1(t1+2)->b1
    if (pre) { LDA_f(afA, 0, 0); STAGE(1, 1, t1 + 2, false); }
    __builtin_amdgcn_s_barrier();
    MM(afB, bfA, 4, 0);
    __builtin_amdgcn_s_barrier();
    // p8: MM Q11(t1)=afB*bfB | pre bfA=bf0(b0,tn) | S8=A0(t1+2)->b1
    if (pre) { LDB_f(bfA, 0, 0); STAGE(1, 0, t1 + 2, true); }
    __builtin_amdgcn_s_barrier();
    MM(afB, bfB, 4, 2);
    __builtin_amdgcn_s_barrier();
  };
  for (int j = 0; j < niter - 1; ++j) ITER(j, true);
  ITER(niter - 1, false);

  // epilogue: C/D frag layout col=lane&15, row=(lane>>4)*4+r  (m89-verified)
  const int col = lane & 15, rb = (lane >> 4) * 4;
#pragma unroll
  for (int mi = 0; mi < 8; ++mi) {
#pragma unroll
    for (int ni = 0; ni < 4; ++ni) {
      const int mg = m0 + wmr * 128 + mi * 16 + rb;
      const int ng = n0 + wnr * 64 + ni * 16 + col;
      const float bvv = BIAS ? bias[ng] : 0.0f;
      if constexpr (CMODE == 2) {
        u16* Cc = (u16*)Cv;
        const long bb = mg >> 11;
        const int  t  = mg & 2047;
        union { u16 us[4]; unsigned long long ll; } u;
#pragma unroll
        for (int r = 0; r < 4; ++r) u.us[r] = f2bf(acc[mi][ni][r] * alpha + bvv);
        *(unsigned long long*)(Cc + bb * 4194304 + (long)ng * 2048 + t) = u.ll;
      } else if constexpr (CMODE == 1) {
        u16* Cc = (u16*)Cv + (long)bz * bsC;
#pragma unroll
        for (int r = 0; r < 4; ++r)
          Cc[(long)(mg + r) * ldc + ng] = f2bf(acc[mi][ni][r] * alpha + bvv);
      } else {
        float* Cf = (float*)Cv + (long)bz * bsC;
#pragma unroll
        for (int r = 0; r < 4; ++r)
          Cf[(long)(mg + r) * ldc + ng] = acc[mi][ni][r] * alpha + bvv;
      }
    }
  }
}

// ---------------- row softmax: fp32 scores row (2048) -> bf16 P in-place --------
__global__ __launch_bounds__(256) void softmax_rows(float* __restrict__ Sc) {
  const int tid = threadIdx.x;
  const long row = blockIdx.x;
  float* srow = Sc + row * 2048;
  const float4 v0 = ((const float4*)srow)[tid * 2];
  const float4 v1 = ((const float4*)srow)[tid * 2 + 1];
  float mx = fmaxf(fmaxf(fmaxf(v0.x, v0.y), fmaxf(v0.z, v0.w)),
                   fmaxf(fmaxf(v1.x, v1.y), fmaxf(v1.z, v1.w)));
  __shared__ float red[8];
  const int lane = tid & 63, wid = tid >> 6;
#pragma unroll
  for (int off = 32; off; off >>= 1) mx = fmaxf(mx, __shfl_down(mx, off));
  if (!lane) red[wid] = mx;
  __syncthreads();
  mx = fmaxf(fmaxf(red[0], red[1]), fmaxf(red[2], red[3]));
  float e[8];
  e[0] = __expf(v0.x - mx); e[1] = __expf(v0.y - mx);
  e[2] = __expf(v0.z - mx); e[3] = __expf(v0.w - mx);
  e[4] = __expf(v1.x - mx); e[5] = __expf(v1.y - mx);
  e[6] = __expf(v1.z - mx); e[7] = __expf(v1.w - mx);
  float s = e[0] + e[1] + e[2] + e[3] + e[4] + e[5] + e[6] + e[7];
#pragma unroll
  for (int off = 32; off; off >>= 1) s += __shfl_down(s, off);
  if (!lane) red[4 + wid] = s;
  __syncthreads();
  s = red[4] + red[5] + red[6] + red[7];
  const float inv = 1.0f / s;
  union { u16 us[8]; int4 v; } u;
#pragma unroll
  for (int j = 0; j < 8; ++j) u.us[j] = f2bf(e[j] * inv);
  ((int4*)srow)[tid] = u.v;
}

extern "C" void kernel_launch(void* const* d_in, const int* in_sizes, int n_in,
                              void* d_out, int out_size, void* d_ws, size_t ws_size,
                              hipStream_t stream) {
  const float* X  = (const float*)d_in[0];
  const float* Wq = (const float*)d_in[1];
  const float* bq = (const float*)d_in[2];
  const float* Wk = (const float*)d_in[3];
  const float* bk = (const float*)d_in[4];
  const float* Wv = (const float*)d_in[5];
  const float* bv = (const float*)d_in[6];
  const float* Wo = (const float*)d_in[7];
  const float* bo = (const float*)d_in[8];
  float* out = (float*)d_out;

  char* w = (char*)d_ws;
  u16* Xb  = (u16*)w; w += (size_t)8192 * 1024 * 2;
  u16* Wqb = (u16*)w; w += (size_t)2048 * 1024 * 2;
  u16* Wkb = (u16*)w; w += (size_t)2048 * 1024 * 2;
  u16* Wvb = (u16*)w; w += (size_t)2048 * 1024 * 2;
  u16* Wob = (u16*)w; w += (size_t)1024 * 2048 * 2;
  u16* Qb  = (u16*)w; w += (size_t)8192 * 2048 * 2;
  u16* Kb  = (u16*)w; w += (size_t)8192 * 2048 * 2;
  u16* Vt  = (u16*)w; w += (size_t)8192 * 2048 * 2;   // [4][2048 d][2048 t]
  u16* AO  = (u16*)w; w += (size_t)8192 * 2048 * 2;
  float* Sc = (float*)w; w += (size_t)4 * 2048 * 2048 * 4;
  if ((size_t)(w - (char*)d_ws) > ws_size) return;

  cvt_f32_bf16<<<8192, 256, 0, stream>>>(X,  Xb,  8192 * 1024 / 4);
  cvt_f32_bf16<<<2048, 256, 0, stream>>>(Wq, Wqb, 2048 * 1024 / 4);
  cvt_f32_bf16<<<2048, 256, 0, stream>>>(Wk, Wkb, 2048 * 1024 / 4);
  cvt_f32_bf16<<<2048, 256, 0, stream>>>(Wv, Wvb, 2048 * 1024 / 4);
  cvt_f32_bf16<<<2048, 256, 0, stream>>>(Wo, Wob, 1024 * 2048 / 4);

  // projections: M=8192, N=2048, K=1024
  gemm256<1, true><<<dim3(8, 32, 1), 512, 0, stream>>>(Xb, Wqb, Qb, bq,
      1024, 1024, 1024, 2048, 0, 0, 0, 1.0f);
  gemm256<1, true><<<dim3(8, 32, 1), 512, 0, stream>>>(Xb, Wkb, Kb, bk,
      1024, 1024, 1024, 2048, 0, 0, 0, 1.0f);
  gemm256<2, true><<<dim3(8, 32, 1), 512, 0, stream>>>(Xb, Wvb, Vt, bv,
      1024, 1024, 1024, 0, 0, 0, 0, 1.0f);

  // scores: per-batch 2048x2048, K=2048, alpha = 1/sqrt(1024)
  gemm256<0, false><<<dim3(8, 8, 4), 512, 0, stream>>>(Qb, Kb, Sc, nullptr,
      2048, 2048, 2048, 2048, 4194304, 4194304, 4194304, 0.03125f);

  softmax_rows<<<8192, 256, 0, stream>>>(Sc);

  // O = P @ Vt^T : A = bf16 P view of Sc (lda 4096)
  gemm256<1, false><<<dim3(8, 8, 4), 512, 0, stream>>>((u16*)Sc, Vt, AO, nullptr,
      2048, 4096, 2048, 2048, 8388608, 4194304, 4194304, 1.0f);

  // out = AO @ Wo^T + bo : M=8192, N=1024, K=2048, fp32 out
  gemm256<0, true><<<dim3(4, 32, 1), 512, 0, stream>>>(AO, Wob, out, bo,
      2048, 2048, 2048, 1024, 0, 0, 0, 1.0f);
}

// Round 7
// 407.043 us; speedup vs baseline: 1.7333x; 1.7333x over previous
//
#include <hip/hip_runtime.h>

// ComplexAttention: B=4, S=2048, D=1024. Reduces to single-head attention with
// head_dim 2*D=2048:  Q/K/V = X@W^T+b ; S = Q@K^T/32 ; P = softmax(S) ; O = P@V ;
// out = O@Wo^T + bo.  GEMMs: 256x256 8-phase bf16 MFMA, reads pipelined 1 phase ahead.
// R7: schedule rebuilt under corrected constraint -- EVERY frag read touches BOTH
// staged halves of its operand tile (wmr/wnr selects the half, not mh/nh), so each
// (operand,buf,tile) must be fully staged+vmcnt-drained before its FIRST read, and
// restaged only >=2 phases after its LAST read (lgkm-forced at read+1's MM + barrier).
// Stages: p3 b0B, p4 b0A (tile t+2); p7 b1B, p8 b1A (t1+2). vmcnt(4) at p3 and p7.

typedef short  bf16x8 __attribute__((ext_vector_type(8)));
typedef float  f32x4  __attribute__((ext_vector_type(4)));
typedef unsigned short u16;

typedef __attribute__((address_space(3))) void       lds_void;
typedef const __attribute__((address_space(1))) void g_void;

#define BAR() asm volatile("s_barrier" ::: "memory")

__device__ __forceinline__ u16 f2bf(float f) {
  union { float f; unsigned u; } v; v.f = f;
  unsigned r = v.u + 0x7FFFu + ((v.u >> 16) & 1u);   // round-to-nearest-even
  return (u16)(r >> 16);
}

// ---------------- fp32 -> bf16 convert (vectorized) ----------------
__global__ __launch_bounds__(256) void cvt_f32_bf16(const float* __restrict__ in,
                                                    u16* __restrict__ out, int n4) {
  int i = blockIdx.x * 256 + threadIdx.x;
  if (i >= n4) return;
  const float4 v = ((const float4*)in)[i];
  union { u16 us[4]; unsigned long long ll; } u;
  u.us[0] = f2bf(v.x); u.us[1] = f2bf(v.y); u.us[2] = f2bf(v.z); u.us[3] = f2bf(v.w);
  ((unsigned long long*)out)[i] = u.ll;
}

// ---------------- 256x256 8-phase NT GEMM ----------------
// C[m,n] = alpha * sum_k A[m,k]*B[n,k] (+ bias[n]).  A,B bf16 row-major (K contig).
// CMODE: 0 = fp32 C, 1 = bf16 C, 2 = bf16 transposed-V write Vt[b][n][t].
// 512 thr = 8 waves (2M x 4N); per-wave 128x64; BK=64; LDS 128 KiB dbuf; XOR swizzle.
// Pipeline: frag read at phase p is consumed by MM at p+1.
//   p1: rd bf1(b0)            | MM Q00(t0)=afA*bfA
//   p2: rd af1(b0)            | MM Q01(t0)=afA*bfB
//   p3: stage b0B(t+2) x2 | vmcnt(4)           | MM Q11(t0)=afB*bfB
//   p4: rd af0(b1),bf0(b1) | stage b0A(t+2) x2 | MM Q10(t0)=afB*bfA
//   p5: rd bf1(b1)            | MM Q00(t1)=afA*bfB
//   p6: rd af1(b1)            | MM Q01(t1)=afA*bfA
//   p7: stage b1B(t1+2) x2 | vmcnt(4)          | MM Q11(t1)=afB*bfA
//   p8: rd af0(b0,t+2),bf0(b0,t+2) | stage b1A(t1+2) x2 | MM Q10(t1)=afB*bfB
// Queue (loads): p3 pre-wait 12 -> vmcnt(4) drains prev b1 stages (4-phase lead);
// p7 pre-wait 12 -> vmcnt(4) drains b0(t+2) stages from p3/p4 (3-phase lead).
template<int CMODE, bool BIAS>
__global__ __launch_bounds__(512, 2) void gemm256(const u16* __restrict__ A,
                                                  const u16* __restrict__ B,
                                                  void* __restrict__ Cv,
                                                  const float* __restrict__ bias,
                                                  int K, int lda, int ldb, int ldc,
                                                  long bsA, long bsB, long bsC,
                                                  float alpha)
{
  __shared__ u16 sm[65536];                  // A: [2][256][64] @ 0 ; B: same @ 32768
  const int bz = blockIdx.z;
  const u16* Ab = A + (long)bz * bsA;
  const u16* Bb = B + (long)bz * bsB;
  const int m0 = blockIdx.y * 256, n0 = blockIdx.x * 256;
  const int tid = threadIdx.x, lane = tid & 63, w = tid >> 6;
  const int wmr = w >> 2, wnr = w & 3;
  const int fr = lane & 15, ko = lane >> 4;

  f32x4 acc[8][4] = {};
  bf16x8 afA[8], afB[8], bfA[4], bfB[4];

  auto STAGE = [&](int dbuf, int half, int t, bool isA) {
    const u16* src = isA ? Ab : Bb;
    const int ld = isA ? lda : ldb;
    const int r0 = (isA ? m0 : n0) + half * 128;
    u16* lb = sm + (isA ? 0 : 32768) + dbuf * 16384 + half * 8192;
#pragma unroll
    for (int q = 0; q < 2; ++q) {
      const int slot = q * 512 + w * 64 + lane;
      const int rl = slot >> 3, cc = slot & 7;
      const int c = cc ^ (rl & 7);
      __builtin_amdgcn_global_load_lds(
          (g_void*)(src + (long)(r0 + rl) * ld + t * 64 + c * 8),
          (lds_void*)(lb + q * 4096 + w * 512), 16, 0, 0);
    }
  };
  auto LDA_f = [&](bf16x8* dst, int dbuf, int mh) {
#pragma unroll
    for (int mi = 0; mi < 4; ++mi)
#pragma unroll
      for (int kk = 0; kk < 2; ++kk) {
        const int r = wmr * 128 + mh * 64 + mi * 16 + fr;
        const int c = kk * 4 + ko;
        dst[mi * 2 + kk] = *(const bf16x8*)(sm + dbuf * 16384 + r * 64 + ((c ^ (r & 7)) * 8));
      }
  };
  auto LDB_f = [&](bf16x8* dst, int dbuf, int nh) {
#pragma unroll
    for (int ni = 0; ni < 2; ++ni)
#pragma unroll
      for (int kk = 0; kk < 2; ++kk) {
        const int r = wnr * 64 + nh * 32 + ni * 16 + fr;
        const int c = kk * 4 + ko;
        dst[ni * 2 + kk] = *(const bf16x8*)(sm + 32768 + dbuf * 16384 + r * 64 + ((c ^ (r & 7)) * 8));
      }
  };
  auto MM = [&](const bf16x8* af, const bf16x8* bf, int mb, int nb) {
    __builtin_amdgcn_s_setprio(1);
#pragma unroll
    for (int mi = 0; mi < 4; ++mi)
#pragma unroll
      for (int ni = 0; ni < 2; ++ni)
#pragma unroll
        for (int kk = 0; kk < 2; ++kk)
          acc[mb + mi][nb + ni] = __builtin_amdgcn_mfma_f32_16x16x32_bf16(
              af[mi * 2 + kk], bf[ni * 2 + kk], acc[mb + mi][nb + ni], 0, 0, 0);
    __builtin_amdgcn_s_setprio(0);
    __builtin_amdgcn_sched_barrier(0);       // keep MFMA cluster + lgkm waits in-phase
  };

  const int nt = K >> 6, niter = nt >> 1;

  // prologue: full b0 (t0) then full b1 (t1); drain b0's 8 loads; pre-read af0/bf0(b0).
  STAGE(0, 0, 0, false); STAGE(0, 1, 0, false);
  STAGE(0, 0, 0, true);  STAGE(0, 1, 0, true);
  STAGE(1, 0, 1, false); STAGE(1, 1, 1, false);
  STAGE(1, 0, 1, true);  STAGE(1, 1, 1, true);
  asm volatile("s_waitcnt vmcnt(8)" ::: "memory");
  BAR();
  LDA_f(afA, 0, 0); LDB_f(bfA, 0, 0);

  for (int j = 0; j < niter; ++j) {
    const bool pre = (j + 1 < niter);
    const int t1 = 2 * j + 1, tn = 2 * j + 2;
    // p1: rd bf1(b0)->bfB | MM Q00(t0)
    LDB_f(bfB, 0, 1);
    BAR();
    MM(afA, bfA, 0, 0);
    BAR();
    // p2: rd af1(b0)->afB | MM Q01(t0)
    LDA_f(afB, 0, 1);
    BAR();
    MM(afA, bfB, 0, 2);
    BAR();
    // p3: stage b0B(tn) | vmcnt(4) drains prev b1 stages | MM Q11(t0)
    if (pre) { STAGE(0, 0, tn, false); STAGE(0, 1, tn, false);
               asm volatile("s_waitcnt vmcnt(4)" ::: "memory"); }
    else     { asm volatile("s_waitcnt vmcnt(0)" ::: "memory"); }
    BAR();
    MM(afB, bfB, 4, 2);
    BAR();
    // p4: rd af0(b1)->afA, bf0(b1)->bfB | stage b0A(tn) | MM Q10(t0)
    LDA_f(afA, 1, 0); LDB_f(bfB, 1, 0);
    if (pre) { STAGE(0, 0, tn, true); STAGE(0, 1, tn, true); }
    BAR();
    MM(afB, bfA, 4, 0);
    BAR();
    // p5: rd bf1(b1)->bfA | MM Q00(t1)
    LDB_f(bfA, 1, 1);
    BAR();
    MM(afA, bfB, 0, 0);
    BAR();
    // p6: rd af1(b1)->afB | MM Q01(t1)
    LDA_f(afB, 1, 1);
    BAR();
    MM(afA, bfA, 0, 2);
    BAR();
    // p7: stage b1B(t1+2) | vmcnt(4) drains b0(tn) stages | MM Q11(t1)
    if (pre) { STAGE(1, 0, t1 + 2, false); STAGE(1, 1, t1 + 2, false);
               asm volatile("s_waitcnt vmcnt(4)" ::: "memory"); }
    BAR();
    MM(afB, bfA, 4, 2);
    BAR();
    // p8: rd af0(b0,tn)->afA, bf0(b0,tn)->bfA | stage b1A(t1+2) | MM Q10(t1)
    if (pre) {
      LDA_f(afA, 0, 0); LDB_f(bfA, 0, 0);
      STAGE(1, 0, t1 + 2, true); STAGE(1, 1, t1 + 2, true);
    }
    BAR();
    MM(afB, bfB, 4, 0);
    BAR();
  }

  // epilogue: C/D frag layout col=lane&15, row=(lane>>4)*4+r  (m89-verified)
  const int col = lane & 15, rb = (lane >> 4) * 4;
#pragma unroll
  for (int mi = 0; mi < 8; ++mi) {
#pragma unroll
    for (int ni = 0; ni < 4; ++ni) {
      const int mg = m0 + wmr * 128 + mi * 16 + rb;
      const int ng = n0 + wnr * 64 + ni * 16 + col;
      const float bvv = BIAS ? bias[ng] : 0.0f;
      if constexpr (CMODE == 2) {
        u16* Cc = (u16*)Cv;
        const long bb = mg >> 11;
        const int  t  = mg & 2047;
        union { u16 us[4]; unsigned long long ll; } u;
#pragma unroll
        for (int r = 0; r < 4; ++r) u.us[r] = f2bf(acc[mi][ni][r] * alpha + bvv);
        *(unsigned long long*)(Cc + bb * 4194304 + (long)ng * 2048 + t) = u.ll;
      } else if constexpr (CMODE == 1) {
        u16* Cc = (u16*)Cv + (long)bz * bsC;
#pragma unroll
        for (int r = 0; r < 4; ++r)
          Cc[(long)(mg + r) * ldc + ng] = f2bf(acc[mi][ni][r] * alpha + bvv);
      } else {
        float* Cf = (float*)Cv + (long)bz * bsC;
#pragma unroll
        for (int r = 0; r < 4; ++r)
          Cf[(long)(mg + r) * ldc + ng] = acc[mi][ni][r] * alpha + bvv;
      }
    }
  }
}

// ---------------- row softmax: fp32 scores row (2048) -> bf16 P in-place --------
__global__ __launch_bounds__(256) void softmax_rows(float* __restrict__ Sc) {
  const int tid = threadIdx.x;
  const long row = blockIdx.x;
  float* srow = Sc + row * 2048;
  const float4 v0 = ((const float4*)srow)[tid * 2];
  const float4 v1 = ((const float4*)srow)[tid * 2 + 1];
  float mx = fmaxf(fmaxf(fmaxf(v0.x, v0.y), fmaxf(v0.z, v0.w)),
                   fmaxf(fmaxf(v1.x, v1.y), fmaxf(v1.z, v1.w)));
  __shared__ float red[8];
  const int lane = tid & 63, wid = tid >> 6;
#pragma unroll
  for (int off = 32; off; off >>= 1) mx = fmaxf(mx, __shfl_down(mx, off));
  if (!lane) red[wid] = mx;
  __syncthreads();
  mx = fmaxf(fmaxf(red[0], red[1]), fmaxf(red[2], red[3]));
  float e[8];
  e[0] = __expf(v0.x - mx); e[1] = __expf(v0.y - mx);
  e[2] = __expf(v0.z - mx); e[3] = __expf(v0.w - mx);
  e[4] = __expf(v1.x - mx); e[5] = __expf(v1.y - mx);
  e[6] = __expf(v1.z - mx); e[7] = __expf(v1.w - mx);
  float s = e[0] + e[1] + e[2] + e[3] + e[4] + e[5] + e[6] + e[7];
#pragma unroll
  for (int off = 32; off; off >>= 1) s += __shfl_down(s, off);
  if (!lane) red[4 + wid] = s;
  __syncthreads();
  s = red[4] + red[5] + red[6] + red[7];
  const float inv = 1.0f / s;
  union { u16 us[8]; int4 v; } u;
#pragma unroll
  for (int j = 0; j < 8; ++j) u.us[j] = f2bf(e[j] * inv);
  ((int4*)srow)[tid] = u.v;
}

extern "C" void kernel_launch(void* const* d_in, const int* in_sizes, int n_in,
                              void* d_out, int out_size, void* d_ws, size_t ws_size,
                              hipStream_t stream) {
  const float* X  = (const float*)d_in[0];
  const float* Wq = (const float*)d_in[1];
  const float* bq = (const float*)d_in[2];
  const float* Wk = (const float*)d_in[3];
  const float* bk = (const float*)d_in[4];
  const float* Wv = (const float*)d_in[5];
  const float* bv = (const float*)d_in[6];
  const float* Wo = (const float*)d_in[7];
  const float* bo = (const float*)d_in[8];
  float* out = (float*)d_out;

  char* w = (char*)d_ws;
  u16* Xb  = (u16*)w; w += (size_t)8192 * 1024 * 2;
  u16* Wqb = (u16*)w; w += (size_t)2048 * 1024 * 2;
  u16* Wkb = (u16*)w; w += (size_t)2048 * 1024 * 2;
  u16* Wvb = (u16*)w; w += (size_t)2048 * 1024 * 2;
  u16* Wob = (u16*)w; w += (size_t)1024 * 2048 * 2;
  u16* Qb  = (u16*)w; w += (size_t)8192 * 2048 * 2;
  u16* Kb  = (u16*)w; w += (size_t)8192 * 2048 * 2;
  u16* Vt  = (u16*)w; w += (size_t)8192 * 2048 * 2;   // [4][2048 d][2048 t]
  u16* AO  = (u16*)w; w += (size_t)8192 * 2048 * 2;
  float* Sc = (float*)w; w += (size_t)4 * 2048 * 2048 * 4;
  if ((size_t)(w - (char*)d_ws) > ws_size) return;

  cvt_f32_bf16<<<8192, 256, 0, stream>>>(X,  Xb,  8192 * 1024 / 4);
  cvt_f32_bf16<<<2048, 256, 0, stream>>>(Wq, Wqb, 2048 * 1024 / 4);
  cvt_f32_bf16<<<2048, 256, 0, stream>>>(Wk, Wkb, 2048 * 1024 / 4);
  cvt_f32_bf16<<<2048, 256, 0, stream>>>(Wv, Wvb, 2048 * 1024 / 4);
  cvt_f32_bf16<<<2048, 256, 0, stream>>>(Wo, Wob, 1024 * 2048 / 4);

  // projections: M=8192, N=2048, K=1024
  gemm256<1, true><<<dim3(8, 32, 1), 512, 0, stream>>>(Xb, Wqb, Qb, bq,
      1024, 1024, 1024, 2048, 0, 0, 0, 1.0f);
  gemm256<1, true><<<dim3(8, 32, 1), 512, 0, stream>>>(Xb, Wkb, Kb, bk,
      1024, 1024, 1024, 2048, 0, 0, 0, 1.0f);
  gemm256<2, true><<<dim3(8, 32, 1), 512, 0, stream>>>(Xb, Wvb, Vt, bv,
      1024, 1024, 1024, 0, 0, 0, 0, 1.0f);

  // scores: per-batch 2048x2048, K=2048, alpha = 1/sqrt(1024)
  gemm256<0, false><<<dim3(8, 8, 4), 512, 0, stream>>>(Qb, Kb, Sc, nullptr,
      2048, 2048, 2048, 2048, 4194304, 4194304, 4194304, 0.03125f);

  softmax_rows<<<8192, 256, 0, stream>>>(Sc);

  // O = P @ Vt^T : A = bf16 P view of Sc (lda 4096)
  gemm256<1, false><<<dim3(8, 8, 4), 512, 0, stream>>>((u16*)Sc, Vt, AO, nullptr,
      2048, 4096, 2048, 2048, 8388608, 4194304, 4194304, 1.0f);

  // out = AO @ Wo^T + bo : M=8192, N=1024, K=2048, fp32 out
  gemm256<0, true><<<dim3(4, 32, 1), 512, 0, stream>>>(AO, Wob, out, bo,
      2048, 2048, 2048, 1024, 0, 0, 0, 1.0f);
}

// Round 8
// 343.997 us; speedup vs baseline: 2.0510x; 1.1833x over previous
//
#include <hip/hip_runtime.h>

// ComplexAttention: B=4, S=2048, D=1024. Reduces to single-head attention with
// head_dim 2*D=2048:  Q/K/V = X@W^T+b ; S = Q@K^T/32 ; P = softmax(S) ; O = P@V ;
// out = O@Wo^T + bo.  GEMMs: 256x256 8-phase bf16 MFMA (m201-style schedule).
// R8: same-phase frag reads (short live ranges, no spill -- R7's 1-phase-ahead reads
// spilled at the 128 arch-VGPR split) + m201 vmcnt discipline: counted vmcnt(4) ONLY
// at p4/p8, full-tile drain, >=3-phase stage->drain lead (R2's defect was 1-phase).

typedef short  bf16x8 __attribute__((ext_vector_type(8)));
typedef float  f32x4  __attribute__((ext_vector_type(4)));
typedef unsigned short u16;

typedef __attribute__((address_space(3))) void       lds_void;
typedef const __attribute__((address_space(1))) void g_void;

#define BAR() asm volatile("s_barrier" ::: "memory")

__device__ __forceinline__ u16 f2bf(float f) {
  union { float f; unsigned u; } v; v.f = f;
  unsigned r = v.u + 0x7FFFu + ((v.u >> 16) & 1u);   // round-to-nearest-even
  return (u16)(r >> 16);
}

// ---------------- fp32 -> bf16 convert (vectorized) ----------------
__global__ __launch_bounds__(256) void cvt_f32_bf16(const float* __restrict__ in,
                                                    u16* __restrict__ out, int n4) {
  int i = blockIdx.x * 256 + threadIdx.x;
  if (i >= n4) return;
  const float4 v = ((const float4*)in)[i];
  union { u16 us[4]; unsigned long long ll; } u;
  u.us[0] = f2bf(v.x); u.us[1] = f2bf(v.y); u.us[2] = f2bf(v.z); u.us[3] = f2bf(v.w);
  ((unsigned long long*)out)[i] = u.ll;
}

// ---------------- 256x256 8-phase NT GEMM ----------------
// C[m,n] = alpha * sum_k A[m,k]*B[n,k] (+ bias[n]).  A,B bf16 row-major (K contig).
// CMODE: 0 = fp32 C, 1 = bf16 C, 2 = bf16 transposed-V write Vt[b][n][t].
// 512 thr = 8 waves (2M x 4N); per-wave 128x64; BK=64; LDS 128 KiB dbuf; XOR swizzle.
// Phase = [ds_reads for THIS MM] [stage] [hints] [BAR] [lgkm0] [16 MFMA] [BAR].
//   p1: rd af0,bf0(b0) 12 | stage b1B(t1) x2   | lgkm(8)   | MM Q00(t0)
//   p2: rd bf1(b0) 4                                       | MM Q01(t0)
//   p3: rd af1(b0) 8                                       | MM Q11(t0)
//   p4: stage b0A(tn) x2 | vmcnt(4|0)                      | MM Q10(t0)
//   p5: rd af0,bf0(b1) 12 | stage b0B(tn) x2   | lgkm(8)   | MM Q00(t1)
//   p6: rd bf1(b1) 4                                       | MM Q01(t1)
//   p7: rd af1(b1) 8                                       | MM Q11(t1)
//   p8: stage b1A(tn+1) x2 | vmcnt(4)                      | MM Q10(t1)
// Queue sim (steady): p4 sees {b1A(p8'),b1B(p1),b0A(p4)}=12 -> vmcnt(4) drains buf1
// fully (leads 4,3 phases); p8 sees {b0A(p4),b0B(p5),b1A(p8)}=12 -> vmcnt(4) drains
// buf0 fully (leads 4,3).  WAR: every region restaged >=2 phases after last read.
template<int CMODE, bool BIAS>
__global__ __launch_bounds__(512, 2) void gemm256(const u16* __restrict__ A,
                                                  const u16* __restrict__ B,
                                                  void* __restrict__ Cv,
                                                  const float* __restrict__ bias,
                                                  int K, int lda, int ldb, int ldc,
                                                  long bsA, long bsB, long bsC,
                                                  float alpha)
{
  __shared__ u16 sm[65536];                  // A: [2][256][64] @ 0 ; B: same @ 32768
  const int bz = blockIdx.z;
  const u16* Ab = A + (long)bz * bsA;
  const u16* Bb = B + (long)bz * bsB;
  const int m0 = blockIdx.y * 256, n0 = blockIdx.x * 256;
  const int tid = threadIdx.x, lane = tid & 63, w = tid >> 6;
  const int wmr = w >> 2, wnr = w & 3;
  const int fr = lane & 15, ko = lane >> 4;

  f32x4 acc[8][4] = {};
  bf16x8 afA[8], afB[8], bfA[4], bfB[4];

  auto STAGE = [&](int dbuf, int half, int t, bool isA) {
    const u16* src = isA ? Ab : Bb;
    const int ld = isA ? lda : ldb;
    const int r0 = (isA ? m0 : n0) + half * 128;
    u16* lb = sm + (isA ? 0 : 32768) + dbuf * 16384 + half * 8192;
#pragma unroll
    for (int q = 0; q < 2; ++q) {
      const int slot = q * 512 + w * 64 + lane;
      const int rl = slot >> 3, cc = slot & 7;
      const int c = cc ^ (rl & 7);
      __builtin_amdgcn_global_load_lds(
          (g_void*)(src + (long)(r0 + rl) * ld + t * 64 + c * 8),
          (lds_void*)(lb + q * 4096 + w * 512), 16, 0, 0);
    }
  };
  auto LDA_f = [&](bf16x8* dst, int dbuf, int mh) {
#pragma unroll
    for (int mi = 0; mi < 4; ++mi)
#pragma unroll
      for (int kk = 0; kk < 2; ++kk) {
        const int r = wmr * 128 + mh * 64 + mi * 16 + fr;
        const int c = kk * 4 + ko;
        dst[mi * 2 + kk] = *(const bf16x8*)(sm + dbuf * 16384 + r * 64 + ((c ^ (r & 7)) * 8));
      }
  };
  auto LDB_f = [&](bf16x8* dst, int dbuf, int nh) {
#pragma unroll
    for (int ni = 0; ni < 2; ++ni)
#pragma unroll
      for (int kk = 0; kk < 2; ++kk) {
        const int r = wnr * 64 + nh * 32 + ni * 16 + fr;
        const int c = kk * 4 + ko;
        dst[ni * 2 + kk] = *(const bf16x8*)(sm + 32768 + dbuf * 16384 + r * 64 + ((c ^ (r & 7)) * 8));
      }
  };
  auto MM = [&](const bf16x8* af, const bf16x8* bf, int mb, int nb) {
    asm volatile("s_waitcnt lgkmcnt(0)" ::: "memory");
    __builtin_amdgcn_sched_barrier(0);
    __builtin_amdgcn_s_setprio(1);
#pragma unroll
    for (int mi = 0; mi < 4; ++mi)
#pragma unroll
      for (int ni = 0; ni < 2; ++ni)
#pragma unroll
        for (int kk = 0; kk < 2; ++kk)
          acc[mb + mi][nb + ni] = __builtin_amdgcn_mfma_f32_16x16x32_bf16(
              af[mi * 2 + kk], bf[ni * 2 + kk], acc[mb + mi][nb + ni], 0, 0, 0);
    __builtin_amdgcn_s_setprio(0);
    __builtin_amdgcn_sched_barrier(0);       // keep MFMA cluster in-phase
  };

  const int nt = K >> 6, niter = nt >> 1;

  // prologue: buf0 full (t=0) + buf1 A halves (t=1); drain buf0 (leave buf1A's 4).
  STAGE(0, 0, 0, true);  STAGE(0, 1, 0, true);
  STAGE(0, 0, 0, false); STAGE(0, 1, 0, false);
  STAGE(1, 0, 1, true);  STAGE(1, 1, 1, true);
  asm volatile("s_waitcnt vmcnt(4)" ::: "memory");
  BAR();

  for (int j = 0; j < niter; ++j) {
    const bool pre = (j + 1 < niter);
    const int t1 = 2 * j + 1, tn = 2 * j + 2;
    // p1: rd af0,bf0(b0) | stage b1B(t1) | MM Q00(t0)
    LDA_f(afA, 0, 0); LDB_f(bfA, 0, 0);
    STAGE(1, 0, t1, false); STAGE(1, 1, t1, false);
    asm volatile("s_waitcnt lgkmcnt(8)" ::: "memory");
    BAR();
    MM(afA, bfA, 0, 0);
    BAR();
    // p2: rd bf1(b0) | MM Q01(t0)
    LDB_f(bfB, 0, 1);
    BAR();
    MM(afA, bfB, 0, 2);
    BAR();
    // p3: rd af1(b0) | MM Q11(t0)
    LDA_f(afB, 0, 1);
    BAR();
    MM(afB, bfB, 4, 2);
    BAR();
    // p4: stage b0A(tn) | vmcnt(4|0) drains buf1 fully | MM Q10(t0)
    if (pre) { STAGE(0, 0, tn, true); STAGE(0, 1, tn, true);
               asm volatile("s_waitcnt vmcnt(4)" ::: "memory"); }
    else     { asm volatile("s_waitcnt vmcnt(0)" ::: "memory"); }
    BAR();
    MM(afB, bfA, 4, 0);
    BAR();
    // p5: rd af0,bf0(b1) | stage b0B(tn) | MM Q00(t1)
    LDA_f(afA, 1, 0); LDB_f(bfA, 1, 0);
    if (pre) { STAGE(0, 0, tn, false); STAGE(0, 1, tn, false); }
    asm volatile("s_waitcnt lgkmcnt(8)" ::: "memory");
    BAR();
    MM(afA, bfA, 0, 0);
    BAR();
    // p6: rd bf1(b1) | MM Q01(t1)
    LDB_f(bfB, 1, 1);
    BAR();
    MM(afA, bfB, 0, 2);
    BAR();
    // p7: rd af1(b1) | MM Q11(t1)
    LDA_f(afB, 1, 1);
    BAR();
    MM(afB, bfB, 4, 2);
    BAR();
    // p8: stage b1A(tn+1) | vmcnt(4) drains buf0 fully | MM Q10(t1)
    if (pre) { STAGE(1, 0, tn + 1, true); STAGE(1, 1, tn + 1, true);
               asm volatile("s_waitcnt vmcnt(4)" ::: "memory"); }
    BAR();
    MM(afB, bfA, 4, 0);
    BAR();
  }

  // epilogue: C/D frag layout col=lane&15, row=(lane>>4)*4+r  (m89-verified)
  const int col = lane & 15, rb = (lane >> 4) * 4;
#pragma unroll
  for (int mi = 0; mi < 8; ++mi) {
#pragma unroll
    for (int ni = 0; ni < 4; ++ni) {
      const int mg = m0 + wmr * 128 + mi * 16 + rb;
      const int ng = n0 + wnr * 64 + ni * 16 + col;
      const float bvv = BIAS ? bias[ng] : 0.0f;
      if constexpr (CMODE == 2) {
        u16* Cc = (u16*)Cv;
        const long bb = mg >> 11;
        const int  t  = mg & 2047;
        union { u16 us[4]; unsigned long long ll; } u;
#pragma unroll
        for (int r = 0; r < 4; ++r) u.us[r] = f2bf(acc[mi][ni][r] * alpha + bvv);
        *(unsigned long long*)(Cc + bb * 4194304 + (long)ng * 2048 + t) = u.ll;
      } else if constexpr (CMODE == 1) {
        u16* Cc = (u16*)Cv + (long)bz * bsC;
#pragma unroll
        for (int r = 0; r < 4; ++r)
          Cc[(long)(mg + r) * ldc + ng] = f2bf(acc[mi][ni][r] * alpha + bvv);
      } else {
        float* Cf = (float*)Cv + (long)bz * bsC;
#pragma unroll
        for (int r = 0; r < 4; ++r)
          Cf[(long)(mg + r) * ldc + ng] = acc[mi][ni][r] * alpha + bvv;
      }
    }
  }
}

// ---------------- row softmax: fp32 scores row (2048) -> bf16 P in-place --------
__global__ __launch_bounds__(256) void softmax_rows(float* __restrict__ Sc) {
  const int tid = threadIdx.x;
  const long row = blockIdx.x;
  float* srow = Sc + row * 2048;
  const float4 v0 = ((const float4*)srow)[tid * 2];
  const float4 v1 = ((const float4*)srow)[tid * 2 + 1];
  float mx = fmaxf(fmaxf(fmaxf(v0.x, v0.y), fmaxf(v0.z, v0.w)),
                   fmaxf(fmaxf(v1.x, v1.y), fmaxf(v1.z, v1.w)));
  __shared__ float red[8];
  const int lane = tid & 63, wid = tid >> 6;
#pragma unroll
  for (int off = 32; off; off >>= 1) mx = fmaxf(mx, __shfl_down(mx, off));
  if (!lane) red[wid] = mx;
  __syncthreads();
  mx = fmaxf(fmaxf(red[0], red[1]), fmaxf(red[2], red[3]));
  float e[8];
  e[0] = __expf(v0.x - mx); e[1] = __expf(v0.y - mx);
  e[2] = __expf(v0.z - mx); e[3] = __expf(v0.w - mx);
  e[4] = __expf(v1.x - mx); e[5] = __expf(v1.y - mx);
  e[6] = __expf(v1.z - mx); e[7] = __expf(v1.w - mx);
  float s = e[0] + e[1] + e[2] + e[3] + e[4] + e[5] + e[6] + e[7];
#pragma unroll
  for (int off = 32; off; off >>= 1) s += __shfl_down(s, off);
  if (!lane) red[4 + wid] = s;
  __syncthreads();
  s = red[4] + red[5] + red[6] + red[7];
  const float inv = 1.0f / s;
  union { u16 us[8]; int4 v; } u;
#pragma unroll
  for (int j = 0; j < 8; ++j) u.us[j] = f2bf(e[j] * inv);
  ((int4*)srow)[tid] = u.v;
}

extern "C" void kernel_launch(void* const* d_in, const int* in_sizes, int n_in,
                              void* d_out, int out_size, void* d_ws, size_t ws_size,
                              hipStream_t stream) {
  const float* X  = (const float*)d_in[0];
  const float* Wq = (const float*)d_in[1];
  const float* bq = (const float*)d_in[2];
  const float* Wk = (const float*)d_in[3];
  const float* bk = (const float*)d_in[4];
  const float* Wv = (const float*)d_in[5];
  const float* bv = (const float*)d_in[6];
  const float* Wo = (const float*)d_in[7];
  const float* bo = (const float*)d_in[8];
  float* out = (float*)d_out;

  char* w = (char*)d_ws;
  u16* Xb  = (u16*)w; w += (size_t)8192 * 1024 * 2;
  u16* Wqb = (u16*)w; w += (size_t)2048 * 1024 * 2;
  u16* Wkb = (u16*)w; w += (size_t)2048 * 1024 * 2;
  u16* Wvb = (u16*)w; w += (size_t)2048 * 1024 * 2;
  u16* Wob = (u16*)w; w += (size_t)1024 * 2048 * 2;
  u16* Qb  = (u16*)w; w += (size_t)8192 * 2048 * 2;
  u16* Kb  = (u16*)w; w += (size_t)8192 * 2048 * 2;
  u16* Vt  = (u16*)w; w += (size_t)8192 * 2048 * 2;   // [4][2048 d][2048 t]
  u16* AO  = (u16*)w; w += (size_t)8192 * 2048 * 2;
  float* Sc = (float*)w; w += (size_t)4 * 2048 * 2048 * 4;
  if ((size_t)(w - (char*)d_ws) > ws_size) return;

  cvt_f32_bf16<<<8192, 256, 0, stream>>>(X,  Xb,  8192 * 1024 / 4);
  cvt_f32_bf16<<<2048, 256, 0, stream>>>(Wq, Wqb, 2048 * 1024 / 4);
  cvt_f32_bf16<<<2048, 256, 0, stream>>>(Wk, Wkb, 2048 * 1024 / 4);
  cvt_f32_bf16<<<2048, 256, 0, stream>>>(Wv, Wvb, 2048 * 1024 / 4);
  cvt_f32_bf16<<<2048, 256, 0, stream>>>(Wo, Wob, 1024 * 2048 / 4);

  // projections: M=8192, N=2048, K=1024
  gemm256<1, true><<<dim3(8, 32, 1), 512, 0, stream>>>(Xb, Wqb, Qb, bq,
      1024, 1024, 1024, 2048, 0, 0, 0, 1.0f);
  gemm256<1, true><<<dim3(8, 32, 1), 512, 0, stream>>>(Xb, Wkb, Kb, bk,
      1024, 1024, 1024, 2048, 0, 0, 0, 1.0f);
  gemm256<2, true><<<dim3(8, 32, 1), 512, 0, stream>>>(Xb, Wvb, Vt, bv,
      1024, 1024, 1024, 0, 0, 0, 0, 1.0f);

  // scores: per-batch 2048x2048, K=2048, alpha = 1/sqrt(1024)
  gemm256<0, false><<<dim3(8, 8, 4), 512, 0, stream>>>(Qb, Kb, Sc, nullptr,
      2048, 2048, 2048, 2048, 4194304, 4194304, 4194304, 0.03125f);

  softmax_rows<<<8192, 256, 0, stream>>>(Sc);

  // O = P @ Vt^T : A = bf16 P view of Sc (lda 4096)
  gemm256<1, false><<<dim3(8, 8, 4), 512, 0, stream>>>((u16*)Sc, Vt, AO, nullptr,
      2048, 4096, 2048, 2048, 8388608, 4194304, 4194304, 1.0f);

  // out = AO @ Wo^T + bo : M=8192, N=1024, K=2048, fp32 out
  gemm256<0, true><<<dim3(4, 32, 1), 512, 0, stream>>>(AO, Wob, out, bo,
      2048, 2048, 2048, 1024, 0, 0, 0, 1.0f);
}

// Round 9
// 337.308 us; speedup vs baseline: 2.0917x; 1.0198x over previous
//
#include <hip/hip_runtime.h>

// ComplexAttention: B=4, S=2048, D=1024. Reduces to single-head attention with
// head_dim 2*D=2048:  Q/K/V = X@W^T+b ; S = Q@K^T/32 ; P = softmax(S) ; O = P@V ;
// out = O@Wo^T + bo.  GEMMs: 256x256 8-phase bf16 MFMA.
// R9: ONE barrier per phase (R8's post-MFMA barrier serialized LDS-read vs MFMA
// across the whole CU -> 37% MfmaUtil plateau).  Safe because every LDS region's
// restage is >=2 phases after its last read: a wave staging in segment p+2 passed
// B(p+1), which all waves reached only after MM(p) (auto-waitcnt => reads complete).
// Staging: b1(t1) @ p1,p2 -> vmcnt(0) @ p4 -> read p5-p8 -> restage p1(next iter).
//          b0(tn) @ p5,p6 -> vmcnt(0) @ p8 -> read p1-p4 (next) -> restage p5(next).
// Drain leads 2-3 phases (>HBM latency) so vmcnt(0) never stalls.  No lgkm asm /
// sched_barrier: frag reads are compiler-tracked (fine-grained auto lgkmcnt).

typedef short  bf16x8 __attribute__((ext_vector_type(8)));
typedef float  f32x4  __attribute__((ext_vector_type(4)));
typedef unsigned short u16;

typedef __attribute__((address_space(3))) void       lds_void;
typedef const __attribute__((address_space(1))) void g_void;

__device__ __forceinline__ u16 f2bf(float f) {
  union { float f; unsigned u; } v; v.f = f;
  unsigned r = v.u + 0x7FFFu + ((v.u >> 16) & 1u);   // round-to-nearest-even
  return (u16)(r >> 16);
}

// ---------------- fp32 -> bf16 convert (vectorized) ----------------
__global__ __launch_bounds__(256) void cvt_f32_bf16(const float* __restrict__ in,
                                                    u16* __restrict__ out, int n4) {
  int i = blockIdx.x * 256 + threadIdx.x;
  if (i >= n4) return;
  const float4 v = ((const float4*)in)[i];
  union { u16 us[4]; unsigned long long ll; } u;
  u.us[0] = f2bf(v.x); u.us[1] = f2bf(v.y); u.us[2] = f2bf(v.z); u.us[3] = f2bf(v.w);
  ((unsigned long long*)out)[i] = u.ll;
}

// ---------------- 256x256 8-phase NT GEMM, 1 barrier/phase ----------------
// C[m,n] = alpha * sum_k A[m,k]*B[n,k] (+ bias[n]).  A,B bf16 row-major (K contig).
// CMODE: 0 = fp32 C, 1 = bf16 C, 2 = bf16 transposed-V write Vt[b][n][t].
// 512 thr = 8 waves (2M x 4N); per-wave 128x64; BK=64; LDS 128 KiB dbuf; XOR swizzle.
//  p1: rd af0,bf0(b0) | stage b1A(t1)   | BAR | MM Q00(t0)
//  p2: rd bf1(b0)     | stage b1B(t1)   | BAR | MM Q01(t0)
//  p3: rd af1(b0)                       | BAR | MM Q11(t0)
//  p4: vmcnt(0) [drains b1(t1)]         | BAR | MM Q10(t0)
//  p5: rd af0,bf0(b1) | stage b0A(tn)*  | BAR | MM Q00(t1)
//  p6: rd bf1(b1)     | stage b0B(tn)*  | BAR | MM Q01(t1)
//  p7: rd af1(b1)                       | BAR | MM Q11(t1)
//  p8: vmcnt(0) [drains b0(tn)]         | BAR | MM Q10(t1)      (* = if pre)
template<int CMODE, bool BIAS>
__global__ __launch_bounds__(512, 2) void gemm256(const u16* __restrict__ A,
                                                  const u16* __restrict__ B,
                                                  void* __restrict__ Cv,
                                                  const float* __restrict__ bias,
                                                  int K, int lda, int ldb, int ldc,
                                                  long bsA, long bsB, long bsC,
                                                  float alpha)
{
  __shared__ u16 sm[65536];                  // A: [2][256][64] @ 0 ; B: same @ 32768
  const int bz = blockIdx.z;
  const u16* Ab = A + (long)bz * bsA;
  const u16* Bb = B + (long)bz * bsB;
  const int m0 = blockIdx.y * 256, n0 = blockIdx.x * 256;
  const int tid = threadIdx.x, lane = tid & 63, w = tid >> 6;
  const int wmr = w >> 2, wnr = w & 3;
  const int fr = lane & 15, ko = lane >> 4;

  f32x4 acc[8][4] = {};
  bf16x8 afA[8], afB[8], bfA[4], bfB[4];

  auto STAGE = [&](int dbuf, int half, int t, bool isA) {
    const u16* src = isA ? Ab : Bb;
    const int ld = isA ? lda : ldb;
    const int r0 = (isA ? m0 : n0) + half * 128;
    u16* lb = sm + (isA ? 0 : 32768) + dbuf * 16384 + half * 8192;
#pragma unroll
    for (int q = 0; q < 2; ++q) {
      const int slot = q * 512 + w * 64 + lane;
      const int rl = slot >> 3, cc = slot & 7;
      const int c = cc ^ (rl & 7);
      __builtin_amdgcn_global_load_lds(
          (g_void*)(src + (long)(r0 + rl) * ld + t * 64 + c * 8),
          (lds_void*)(lb + q * 4096 + w * 512), 16, 0, 0);
    }
  };
  auto LDA_f = [&](bf16x8* dst, int dbuf, int mh) {
#pragma unroll
    for (int mi = 0; mi < 4; ++mi)
#pragma unroll
      for (int kk = 0; kk < 2; ++kk) {
        const int r = wmr * 128 + mh * 64 + mi * 16 + fr;
        const int c = kk * 4 + ko;
        dst[mi * 2 + kk] = *(const bf16x8*)(sm + dbuf * 16384 + r * 64 + ((c ^ (r & 7)) * 8));
      }
  };
  auto LDB_f = [&](bf16x8* dst, int dbuf, int nh) {
#pragma unroll
    for (int ni = 0; ni < 2; ++ni)
#pragma unroll
      for (int kk = 0; kk < 2; ++kk) {
        const int r = wnr * 64 + nh * 32 + ni * 16 + fr;
        const int c = kk * 4 + ko;
        dst[ni * 2 + kk] = *(const bf16x8*)(sm + 32768 + dbuf * 16384 + r * 64 + ((c ^ (r & 7)) * 8));
      }
  };
  auto MM = [&](const bf16x8* af, const bf16x8* bf, int mb, int nb) {
    __builtin_amdgcn_s_setprio(1);
#pragma unroll
    for (int mi = 0; mi < 4; ++mi)
#pragma unroll
      for (int ni = 0; ni < 2; ++ni)
#pragma unroll
        for (int kk = 0; kk < 2; ++kk)
          acc[mb + mi][nb + ni] = __builtin_amdgcn_mfma_f32_16x16x32_bf16(
              af[mi * 2 + kk], bf[ni * 2 + kk], acc[mb + mi][nb + ni], 0, 0, 0);
    __builtin_amdgcn_s_setprio(0);
  };

  const int nt = K >> 6, niter = nt >> 1;

  // prologue: buf0 full (t=0); drain; barrier.
  STAGE(0, 0, 0, true);  STAGE(0, 1, 0, true);
  STAGE(0, 0, 0, false); STAGE(0, 1, 0, false);
  asm volatile("s_waitcnt vmcnt(0)" ::: "memory");
  __builtin_amdgcn_s_barrier();

  for (int j = 0; j < niter; ++j) {
    const bool pre = (j + 1 < niter);
    const int t1 = 2 * j + 1, tn = 2 * j + 2;
    // p1: rd af0,bf0(b0) | stage b1A(t1) | MM Q00(t0)
    LDA_f(afA, 0, 0); LDB_f(bfA, 0, 0);
    STAGE(1, 0, t1, true); STAGE(1, 1, t1, true);
    __builtin_amdgcn_s_barrier();
    MM(afA, bfA, 0, 0);
    // p2: rd bf1(b0) | stage b1B(t1) | MM Q01(t0)
    LDB_f(bfB, 0, 1);
    STAGE(1, 0, t1, false); STAGE(1, 1, t1, false);
    __builtin_amdgcn_s_barrier();
    MM(afA, bfB, 0, 2);
    // p3: rd af1(b0) | MM Q11(t0)
    LDA_f(afB, 0, 1);
    __builtin_amdgcn_s_barrier();
    MM(afB, bfB, 4, 2);
    // p4: drain b1(t1) | MM Q10(t0)
    asm volatile("s_waitcnt vmcnt(0)" ::: "memory");
    __builtin_amdgcn_s_barrier();
    MM(afB, bfA, 4, 0);
    // p5: rd af0,bf0(b1) | stage b0A(tn) | MM Q00(t1)
    LDA_f(afA, 1, 0); LDB_f(bfA, 1, 0);
    if (pre) { STAGE(0, 0, tn, true); STAGE(0, 1, tn, true); }
    __builtin_amdgcn_s_barrier();
    MM(afA, bfA, 0, 0);
    // p6: rd bf1(b1) | stage b0B(tn) | MM Q01(t1)
    LDB_f(bfB, 1, 1);
    if (pre) { STAGE(0, 0, tn, false); STAGE(0, 1, tn, false); }
    __builtin_amdgcn_s_barrier();
    MM(afA, bfB, 0, 2);
    // p7: rd af1(b1) | MM Q11(t1)
    LDA_f(afB, 1, 1);
    __builtin_amdgcn_s_barrier();
    MM(afB, bfB, 4, 2);
    // p8: drain b0(tn) | MM Q10(t1)
    asm volatile("s_waitcnt vmcnt(0)" ::: "memory");
    __builtin_amdgcn_s_barrier();
    MM(afB, bfA, 4, 0);
  }

  // epilogue: C/D frag layout col=lane&15, row=(lane>>4)*4+r  (m89-verified)
  const int col = lane & 15, rb = (lane >> 4) * 4;
#pragma unroll
  for (int mi = 0; mi < 8; ++mi) {
#pragma unroll
    for (int ni = 0; ni < 4; ++ni) {
      const int mg = m0 + wmr * 128 + mi * 16 + rb;
      const int ng = n0 + wnr * 64 + ni * 16 + col;
      const float bvv = BIAS ? bias[ng] : 0.0f;
      if constexpr (CMODE == 2) {
        u16* Cc = (u16*)Cv;
        const long bb = mg >> 11;
        const int  t  = mg & 2047;
        union { u16 us[4]; unsigned long long ll; } u;
#pragma unroll
        for (int r = 0; r < 4; ++r) u.us[r] = f2bf(acc[mi][ni][r] * alpha + bvv);
        *(unsigned long long*)(Cc + bb * 4194304 + (long)ng * 2048 + t) = u.ll;
      } else if constexpr (CMODE == 1) {
        u16* Cc = (u16*)Cv + (long)bz * bsC;
#pragma unroll
        for (int r = 0; r < 4; ++r)
          Cc[(long)(mg + r) * ldc + ng] = f2bf(acc[mi][ni][r] * alpha + bvv);
      } else {
        float* Cf = (float*)Cv + (long)bz * bsC;
#pragma unroll
        for (int r = 0; r < 4; ++r)
          Cf[(long)(mg + r) * ldc + ng] = acc[mi][ni][r] * alpha + bvv;
      }
    }
  }
}

// ---------------- row softmax: fp32 scores row (2048) -> bf16 P in-place --------
__global__ __launch_bounds__(256) void softmax_rows(float* __restrict__ Sc) {
  const int tid = threadIdx.x;
  const long row = blockIdx.x;
  float* srow = Sc + row * 2048;
  const float4 v0 = ((const float4*)srow)[tid * 2];
  const float4 v1 = ((const float4*)srow)[tid * 2 + 1];
  float mx = fmaxf(fmaxf(fmaxf(v0.x, v0.y), fmaxf(v0.z, v0.w)),
                   fmaxf(fmaxf(v1.x, v1.y), fmaxf(v1.z, v1.w)));
  __shared__ float red[8];
  const int lane = tid & 63, wid = tid >> 6;
#pragma unroll
  for (int off = 32; off; off >>= 1) mx = fmaxf(mx, __shfl_down(mx, off));
  if (!lane) red[wid] = mx;
  __syncthreads();
  mx = fmaxf(fmaxf(red[0], red[1]), fmaxf(red[2], red[3]));
  float e[8];
  e[0] = __expf(v0.x - mx); e[1] = __expf(v0.y - mx);
  e[2] = __expf(v0.z - mx); e[3] = __expf(v0.w - mx);
  e[4] = __expf(v1.x - mx); e[5] = __expf(v1.y - mx);
  e[6] = __expf(v1.z - mx); e[7] = __expf(v1.w - mx);
  float s = e[0] + e[1] + e[2] + e[3] + e[4] + e[5] + e[6] + e[7];
#pragma unroll
  for (int off = 32; off; off >>= 1) s += __shfl_down(s, off);
  if (!lane) red[4 + wid] = s;
  __syncthreads();
  s = red[4] + red[5] + red[6] + red[7];
  const float inv = 1.0f / s;
  union { u16 us[8]; int4 v; } u;
#pragma unroll
  for (int j = 0; j < 8; ++j) u.us[j] = f2bf(e[j] * inv);
  ((int4*)srow)[tid] = u.v;
}

extern "C" void kernel_launch(void* const* d_in, const int* in_sizes, int n_in,
                              void* d_out, int out_size, void* d_ws, size_t ws_size,
                              hipStream_t stream) {
  const float* X  = (const float*)d_in[0];
  const float* Wq = (const float*)d_in[1];
  const float* bq = (const float*)d_in[2];
  const float* Wk = (const float*)d_in[3];
  const float* bk = (const float*)d_in[4];
  const float* Wv = (const float*)d_in[5];
  const float* bv = (const float*)d_in[6];
  const float* Wo = (const float*)d_in[7];
  const float* bo = (const float*)d_in[8];
  float* out = (float*)d_out;

  char* w = (char*)d_ws;
  u16* Xb  = (u16*)w; w += (size_t)8192 * 1024 * 2;
  u16* Wqb = (u16*)w; w += (size_t)2048 * 1024 * 2;
  u16* Wkb = (u16*)w; w += (size_t)2048 * 1024 * 2;
  u16* Wvb = (u16*)w; w += (size_t)2048 * 1024 * 2;
  u16* Wob = (u16*)w; w += (size_t)1024 * 2048 * 2;
  u16* Qb  = (u16*)w; w += (size_t)8192 * 2048 * 2;
  u16* Kb  = (u16*)w; w += (size_t)8192 * 2048 * 2;
  u16* Vt  = (u16*)w; w += (size_t)8192 * 2048 * 2;   // [4][2048 d][2048 t]
  u16* AO  = (u16*)w; w += (size_t)8192 * 2048 * 2;
  float* Sc = (float*)w; w += (size_t)4 * 2048 * 2048 * 4;
  if ((size_t)(w - (char*)d_ws) > ws_size) return;

  cvt_f32_bf16<<<8192, 256, 0, stream>>>(X,  Xb,  8192 * 1024 / 4);
  cvt_f32_bf16<<<2048, 256, 0, stream>>>(Wq, Wqb, 2048 * 1024 / 4);
  cvt_f32_bf16<<<2048, 256, 0, stream>>>(Wk, Wkb, 2048 * 1024 / 4);
  cvt_f32_bf16<<<2048, 256, 0, stream>>>(Wv, Wvb, 2048 * 1024 / 4);
  cvt_f32_bf16<<<2048, 256, 0, stream>>>(Wo, Wob, 1024 * 2048 / 4);

  // projections: M=8192, N=2048, K=1024
  gemm256<1, true><<<dim3(8, 32, 1), 512, 0, stream>>>(Xb, Wqb, Qb, bq,
      1024, 1024, 1024, 2048, 0, 0, 0, 1.0f);
  gemm256<1, true><<<dim3(8, 32, 1), 512, 0, stream>>>(Xb, Wkb, Kb, bk,
      1024, 1024, 1024, 2048, 0, 0, 0, 1.0f);
  gemm256<2, true><<<dim3(8, 32, 1), 512, 0, stream>>>(Xb, Wvb, Vt, bv,
      1024, 1024, 1024, 0, 0, 0, 0, 1.0f);

  // scores: per-batch 2048x2048, K=2048, alpha = 1/sqrt(1024)
  gemm256<0, false><<<dim3(8, 8, 4), 512, 0, stream>>>(Qb, Kb, Sc, nullptr,
      2048, 2048, 2048, 2048, 4194304, 4194304, 4194304, 0.03125f);

  softmax_rows<<<8192, 256, 0, stream>>>(Sc);

  // O = P @ Vt^T : A = bf16 P view of Sc (lda 4096)
  gemm256<1, false><<<dim3(8, 8, 4), 512, 0, stream>>>((u16*)Sc, Vt, AO, nullptr,
      2048, 4096, 2048, 2048, 8388608, 4194304, 4194304, 1.0f);

  // out = AO @ Wo^T + bo : M=8192, N=1024, K=2048, fp32 out
  gemm256<0, true><<<dim3(4, 32, 1), 512, 0, stream>>>(AO, Wob, out, bo,
      2048, 2048, 2048, 1024, 0, 0, 0, 1.0f);
}

// Round 10
// 320.301 us; speedup vs baseline: 2.2028x; 1.0531x over previous
//
#include <hip/hip_runtime.h>

// ComplexAttention: B=4, S=2048, D=1024. Reduces to single-head attention with
// head_dim 2*D=2048:  Q/K/V = X@W^T+b ; S = Q@K^T/32 ; P = softmax(S) ; O = P@V ;
// out = O@Wo^T + bo.  GEMMs: 256x256 bf16 MFMA.
// R10: 2-phase SEGMENTS (4 barriers/iter).  R9's {reads|bar|MFMA} phases serialized
// the LDS pipe vs matrix pipe CU-wide (iter ~= LDS+MFMA sum).  Now reads+stages sit
// INSIDE the segment interleaved with two MFMA clusters -> pipes overlap (target
// iter ~= max(LDS,MFMA)).  All reads AFTER the opening barrier (cross-wave RAW/WAR
// re-derived; reads-before-bar would race with other waves' in-flight ops).

typedef short  bf16x8 __attribute__((ext_vector_type(8)));
typedef float  f32x4  __attribute__((ext_vector_type(4)));
typedef unsigned short u16;

typedef __attribute__((address_space(3))) void       lds_void;
typedef const __attribute__((address_space(1))) void g_void;

#define BARA() asm volatile("s_barrier" ::: "memory")

__device__ __forceinline__ u16 f2bf(float f) {
  union { float f; unsigned u; } v; v.f = f;
  unsigned r = v.u + 0x7FFFu + ((v.u >> 16) & 1u);   // round-to-nearest-even
  return (u16)(r >> 16);
}

// ---------------- fp32 -> bf16 convert (vectorized) ----------------
__global__ __launch_bounds__(256) void cvt_f32_bf16(const float* __restrict__ in,
                                                    u16* __restrict__ out, int n4) {
  int i = blockIdx.x * 256 + threadIdx.x;
  if (i >= n4) return;
  const float4 v = ((const float4*)in)[i];
  union { u16 us[4]; unsigned long long ll; } u;
  u.us[0] = f2bf(v.x); u.us[1] = f2bf(v.y); u.us[2] = f2bf(v.z); u.us[3] = f2bf(v.w);
  ((unsigned long long*)out)[i] = u.ll;
}

// ---------------- 256x256 NT GEMM, 4 barriers / (2 K-tiles) ----------------
// C[m,n] = alpha * sum_k A[m,k]*B[n,k] (+ bias[n]).  A,B bf16 row-major (K contig).
// CMODE: 0 = fp32 C, 1 = bf16 C, 2 = bf16 transposed-V write Vt[b][n][t].
// 512 thr = 8 waves (2M x 4N); per-wave 128x64; BK=64; LDS 128 KiB dbuf; XOR swizzle.
// Iter (t0 in buf0, t1 in buf1):
//  S1: BAR | rd af0,bf0(b0); stg b1A(t1); MMQ00 | rd bf1(b0); stg b1B(t1); MMQ01
//  S2: BAR | rd af1(b0); MMQ11 | vmcnt(0) [drains b1]; MMQ10
//  S3: BAR | rd af0,bf0(b1); stg b0A(tn)*; MMQ00' | rd bf1(b1); stg b0B(tn)*; MMQ01'
//  S4: BAR | rd af1(b1); MMQ11' | vmcnt(0) [drains b0(tn)]; MMQ10'     (*if pre)
// RAW: b0 reads follow prev S4 vmcnt + bar1; b1 reads follow S2 vmcnt + bar3.
// WAR: b1 restage (S1) >=1 bar after S4's last b1 read; b0 restage (S3) >=1 bar
// after S2's last b0 read.  vmcnt(0) leads ~1+ phase > HBM latency.
template<int CMODE, bool BIAS>
__global__ __launch_bounds__(512, 2) void gemm256(const u16* __restrict__ A,
                                                  const u16* __restrict__ B,
                                                  void* __restrict__ Cv,
                                                  const float* __restrict__ bias,
                                                  int K, int lda, int ldb, int ldc,
                                                  long bsA, long bsB, long bsC,
                                                  float alpha)
{
  __shared__ u16 sm[65536];                  // A: [2][256][64] @ 0 ; B: same @ 32768
  const int bz = blockIdx.z;
  const u16* Ab = A + (long)bz * bsA;
  const u16* Bb = B + (long)bz * bsB;
  const int m0 = blockIdx.y * 256, n0 = blockIdx.x * 256;
  const int tid = threadIdx.x, lane = tid & 63, w = tid >> 6;
  const int wmr = w >> 2, wnr = w & 3;
  const int fr = lane & 15, ko = lane >> 4;

  f32x4 acc[8][4] = {};
  bf16x8 afA[8], afB[8], bfA[4], bfB[4];

  auto STAGE = [&](int dbuf, int half, int t, bool isA) {
    const u16* src = isA ? Ab : Bb;
    const int ld = isA ? lda : ldb;
    const int r0 = (isA ? m0 : n0) + half * 128;
    u16* lb = sm + (isA ? 0 : 32768) + dbuf * 16384 + half * 8192;
#pragma unroll
    for (int q = 0; q < 2; ++q) {
      const int slot = q * 512 + w * 64 + lane;
      const int rl = slot >> 3, cc = slot & 7;
      const int c = cc ^ (rl & 7);
      __builtin_amdgcn_global_load_lds(
          (g_void*)(src + (long)(r0 + rl) * ld + t * 64 + c * 8),
          (lds_void*)(lb + q * 4096 + w * 512), 16, 0, 0);
    }
  };
  auto LDA_f = [&](bf16x8* dst, int dbuf, int mh) {
#pragma unroll
    for (int mi = 0; mi < 4; ++mi)
#pragma unroll
      for (int kk = 0; kk < 2; ++kk) {
        const int r = wmr * 128 + mh * 64 + mi * 16 + fr;
        const int c = kk * 4 + ko;
        dst[mi * 2 + kk] = *(const bf16x8*)(sm + dbuf * 16384 + r * 64 + ((c ^ (r & 7)) * 8));
      }
  };
  auto LDB_f = [&](bf16x8* dst, int dbuf, int nh) {
#pragma unroll
    for (int ni = 0; ni < 2; ++ni)
#pragma unroll
      for (int kk = 0; kk < 2; ++kk) {
        const int r = wnr * 64 + nh * 32 + ni * 16 + fr;
        const int c = kk * 4 + ko;
        dst[ni * 2 + kk] = *(const bf16x8*)(sm + 32768 + dbuf * 16384 + r * 64 + ((c ^ (r & 7)) * 8));
      }
  };
  auto MM = [&](const bf16x8* af, const bf16x8* bf, int mb, int nb) {
    __builtin_amdgcn_s_setprio(1);
#pragma unroll
    for (int mi = 0; mi < 4; ++mi)
#pragma unroll
      for (int ni = 0; ni < 2; ++ni)
#pragma unroll
        for (int kk = 0; kk < 2; ++kk)
          acc[mb + mi][nb + ni] = __builtin_amdgcn_mfma_f32_16x16x32_bf16(
              af[mi * 2 + kk], bf[ni * 2 + kk], acc[mb + mi][nb + ni], 0, 0, 0);
    __builtin_amdgcn_s_setprio(0);
  };

  const int nt = K >> 6, niter = nt >> 1;

  // prologue: buf0 full (t=0); drain; barrier.
  STAGE(0, 0, 0, true);  STAGE(0, 1, 0, true);
  STAGE(0, 0, 0, false); STAGE(0, 1, 0, false);
  asm volatile("s_waitcnt vmcnt(0)" ::: "memory");
  __builtin_amdgcn_s_barrier();

  for (int j = 0; j < niter; ++j) {
    const bool pre = (j + 1 < niter);
    const int t1 = 2 * j + 1, tn = 2 * j + 2;
    // S1
    BARA();
    LDA_f(afA, 0, 0); LDB_f(bfA, 0, 0);
    STAGE(1, 0, t1, true); STAGE(1, 1, t1, true);
    MM(afA, bfA, 0, 0);
    LDB_f(bfB, 0, 1);
    STAGE(1, 0, t1, false); STAGE(1, 1, t1, false);
    MM(afA, bfB, 0, 2);
    // S2
    BARA();
    LDA_f(afB, 0, 1);
    MM(afB, bfB, 4, 2);
    asm volatile("s_waitcnt vmcnt(0)" ::: "memory");   // drains b1(t1) stages
    MM(afB, bfA, 4, 0);
    // S3
    BARA();
    LDA_f(afA, 1, 0); LDB_f(bfA, 1, 0);
    if (pre) { STAGE(0, 0, tn, true); STAGE(0, 1, tn, true); }
    MM(afA, bfA, 0, 0);
    LDB_f(bfB, 1, 1);
    if (pre) { STAGE(0, 0, tn, false); STAGE(0, 1, tn, false); }
    MM(afA, bfB, 0, 2);
    // S4
    BARA();
    LDA_f(afB, 1, 1);
    MM(afB, bfB, 4, 2);
    asm volatile("s_waitcnt vmcnt(0)" ::: "memory");   // drains b0(tn) stages
    MM(afB, bfA, 4, 0);
  }

  // epilogue: C/D frag layout col=lane&15, row=(lane>>4)*4+r  (m89-verified)
  const int col = lane & 15, rb = (lane >> 4) * 4;
#pragma unroll
  for (int mi = 0; mi < 8; ++mi) {
#pragma unroll
    for (int ni = 0; ni < 4; ++ni) {
      const int mg = m0 + wmr * 128 + mi * 16 + rb;
      const int ng = n0 + wnr * 64 + ni * 16 + col;
      const float bvv = BIAS ? bias[ng] : 0.0f;
      if constexpr (CMODE == 2) {
        u16* Cc = (u16*)Cv;
        const long bb = mg >> 11;
        const int  t  = mg & 2047;
        union { u16 us[4]; unsigned long long ll; } u;
#pragma unroll
        for (int r = 0; r < 4; ++r) u.us[r] = f2bf(acc[mi][ni][r] * alpha + bvv);
        *(unsigned long long*)(Cc + bb * 4194304 + (long)ng * 2048 + t) = u.ll;
      } else if constexpr (CMODE == 1) {
        u16* Cc = (u16*)Cv + (long)bz * bsC;
#pragma unroll
        for (int r = 0; r < 4; ++r)
          Cc[(long)(mg + r) * ldc + ng] = f2bf(acc[mi][ni][r] * alpha + bvv);
      } else {
        float* Cf = (float*)Cv + (long)bz * bsC;
#pragma unroll
        for (int r = 0; r < 4; ++r)
          Cf[(long)(mg + r) * ldc + ng] = acc[mi][ni][r] * alpha + bvv;
      }
    }
  }
}

// ---------------- row softmax: fp32 scores row (2048) -> bf16 P in-place --------
__global__ __launch_bounds__(256) void softmax_rows(float* __restrict__ Sc) {
  const int tid = threadIdx.x;
  const long row = blockIdx.x;
  float* srow = Sc + row * 2048;
  const float4 v0 = ((const float4*)srow)[tid * 2];
  const float4 v1 = ((const float4*)srow)[tid * 2 + 1];
  float mx = fmaxf(fmaxf(fmaxf(v0.x, v0.y), fmaxf(v0.z, v0.w)),
                   fmaxf(fmaxf(v1.x, v1.y), fmaxf(v1.z, v1.w)));
  __shared__ float red[8];
  const int lane = tid & 63, wid = tid >> 6;
#pragma unroll
  for (int off = 32; off; off >>= 1) mx = fmaxf(mx, __shfl_down(mx, off));
  if (!lane) red[wid] = mx;
  __syncthreads();
  mx = fmaxf(fmaxf(red[0], red[1]), fmaxf(red[2], red[3]));
  float e[8];
  e[0] = __expf(v0.x - mx); e[1] = __expf(v0.y - mx);
  e[2] = __expf(v0.z - mx); e[3] = __expf(v0.w - mx);
  e[4] = __expf(v1.x - mx); e[5] = __expf(v1.y - mx);
  e[6] = __expf(v1.z - mx); e[7] = __expf(v1.w - mx);
  float s = e[0] + e[1] + e[2] + e[3] + e[4] + e[5] + e[6] + e[7];
#pragma unroll
  for (int off = 32; off; off >>= 1) s += __shfl_down(s, off);
  if (!lane) red[4 + wid] = s;
  __syncthreads();
  s = red[4] + red[5] + red[6] + red[7];
  const float inv = 1.0f / s;
  union { u16 us[8]; int4 v; } u;
#pragma unroll
  for (int j = 0; j < 8; ++j) u.us[j] = f2bf(e[j] * inv);
  ((int4*)srow)[tid] = u.v;
}

extern "C" void kernel_launch(void* const* d_in, const int* in_sizes, int n_in,
                              void* d_out, int out_size, void* d_ws, size_t ws_size,
                              hipStream_t stream) {
  const float* X  = (const float*)d_in[0];
  const float* Wq = (const float*)d_in[1];
  const float* bq = (const float*)d_in[2];
  const float* Wk = (const float*)d_in[3];
  const float* bk = (const float*)d_in[4];
  const float* Wv = (const float*)d_in[5];
  const float* bv = (const float*)d_in[6];
  const float* Wo = (const float*)d_in[7];
  const float* bo = (const float*)d_in[8];
  float* out = (float*)d_out;

  char* w = (char*)d_ws;
  u16* Xb  = (u16*)w; w += (size_t)8192 * 1024 * 2;
  u16* Wqb = (u16*)w; w += (size_t)2048 * 1024 * 2;
  u16* Wkb = (u16*)w; w += (size_t)2048 * 1024 * 2;
  u16* Wvb = (u16*)w; w += (size_t)2048 * 1024 * 2;
  u16* Wob = (u16*)w; w += (size_t)1024 * 2048 * 2;
  u16* Qb  = (u16*)w; w += (size_t)8192 * 2048 * 2;
  u16* Kb  = (u16*)w; w += (size_t)8192 * 2048 * 2;
  u16* Vt  = (u16*)w; w += (size_t)8192 * 2048 * 2;   // [4][2048 d][2048 t]
  u16* AO  = (u16*)w; w += (size_t)8192 * 2048 * 2;
  float* Sc = (float*)w; w += (size_t)4 * 2048 * 2048 * 4;
  if ((size_t)(w - (char*)d_ws) > ws_size) return;

  cvt_f32_bf16<<<8192, 256, 0, stream>>>(X,  Xb,  8192 * 1024 / 4);
  cvt_f32_bf16<<<2048, 256, 0, stream>>>(Wq, Wqb, 2048 * 1024 / 4);
  cvt_f32_bf16<<<2048, 256, 0, stream>>>(Wk, Wkb, 2048 * 1024 / 4);
  cvt_f32_bf16<<<2048, 256, 0, stream>>>(Wv, Wvb, 2048 * 1024 / 4);
  cvt_f32_bf16<<<2048, 256, 0, stream>>>(Wo, Wob, 1024 * 2048 / 4);

  // projections: M=8192, N=2048, K=1024
  gemm256<1, true><<<dim3(8, 32, 1), 512, 0, stream>>>(Xb, Wqb, Qb, bq,
      1024, 1024, 1024, 2048, 0, 0, 0, 1.0f);
  gemm256<1, true><<<dim3(8, 32, 1), 512, 0, stream>>>(Xb, Wkb, Kb, bk,
      1024, 1024, 1024, 2048, 0, 0, 0, 1.0f);
  gemm256<2, true><<<dim3(8, 32, 1), 512, 0, stream>>>(Xb, Wvb, Vt, bv,
      1024, 1024, 1024, 0, 0, 0, 0, 1.0f);

  // scores: per-batch 2048x2048, K=2048, alpha = 1/sqrt(1024)
  gemm256<0, false><<<dim3(8, 8, 4), 512, 0, stream>>>(Qb, Kb, Sc, nullptr,
      2048, 2048, 2048, 2048, 4194304, 4194304, 4194304, 0.03125f);

  softmax_rows<<<8192, 256, 0, stream>>>(Sc);

  // O = P @ Vt^T : A = bf16 P view of Sc (lda 4096)
  gemm256<1, false><<<dim3(8, 8, 4), 512, 0, stream>>>((u16*)Sc, Vt, AO, nullptr,
      2048, 4096, 2048, 2048, 8388608, 4194304, 4194304, 1.0f);

  // out = AO @ Wo^T + bo : M=8192, N=1024, K=2048, fp32 out
  gemm256<0, true><<<dim3(4, 32, 1), 512, 0, stream>>>(AO, Wob, out, bo,
      2048, 2048, 2048, 1024, 0, 0, 0, 1.0f);
}